// Round 5
// baseline (67.454 us; speedup 1.0000x reference)
//
#include <hip/hip_runtime.h>
#include <hip/hip_bf16.h>
#include <math.h>

// Problem constants (b=2, L=4096, H=16, dh=ds=64, CHUNK=64)
#define LSEQ 4096
#define NH   16
#define DH   64
#define CH   64
#define NCH  64
#define LDT  72   // bf16 LDS row stride (144B): 16B-aligned rows

typedef __attribute__((ext_vector_type(8))) short bf16x8;
typedef __attribute__((ext_vector_type(4))) short s16x4;
typedef __attribute__((ext_vector_type(4))) float f32x4;

#define MFMA16(a, b, c) __builtin_amdgcn_mfma_f32_16x16x32_bf16((a), (b), (c), 0, 0, 0)

__device__ __forceinline__ float4 ld4(const float* p) {
    return *reinterpret_cast<const float4*>(p);
}
__device__ __forceinline__ short f2b(float x) {
    __hip_bfloat16 h = __float2bfloat16(x);
    return *reinterpret_cast<short*>(&h);
}
__device__ __forceinline__ float b2f(short s) {
    union { unsigned u; float f; } v;
    v.u = ((unsigned)(unsigned short)s) << 16;
    return v.f;
}
__device__ __forceinline__ s16x4 pack4(float a, float b, float c, float d) {
    s16x4 r; r.x = f2b(a); r.y = f2b(b); r.z = f2b(c); r.w = f2b(d); return r;
}
__device__ __forceinline__ uint2 sx2(uint2 v, int m) {
    uint2 r;
    r.x = (unsigned)__shfl_xor((int)v.x, m, 64);
    r.y = (unsigned)__shfl_xor((int)v.y, m, 64);
    return r;
}
__device__ __forceinline__ short ext4(uint2 u, int g) {
    unsigned word = (g & 2) ? u.y : u.x;
    return (short)((g & 1) ? (word >> 16) : (word & 0xffffu));
}
// Barrier that drains LDS only (NOT vmcnt) — keeps prefetch global loads in
// flight across phase edges. All 256 threads execute it unconditionally.
__device__ __forceinline__ void barrier_lds() {
    __builtin_amdgcn_sched_barrier(0);
    asm volatile("s_waitcnt lgkmcnt(0)" ::: "memory");
    __builtin_amdgcn_s_barrier();
    __builtin_amdgcn_sched_barrier(0);
}

// ---------------------------------------------------------------------------
// Kernel 1: per-chunk MFMA work, 2 chunks per block, software-pipelined.
// Grid 1024 = (b,h) x 32 chunk-pairs; 256 threads = 4 waves; ~27.7 KB LDS.
// Schedule per chunk: stage(from regs) [+issue next chunk's loads] -> bar ->
//   GX/GB/CB MFMA + surprise reduce -> bar -> gate+scan (all waves, shfl) +
//   T->R3 + bfly-transpose read R1,R2 -> bar -> transposed writes -> bar ->
//   Y_intra^T & h_final MFMA -> global stores.
// Fragment map (m89-verified 16x16x32 bf16):
//   A: lane = A[row=rb+(lane&15)][k=8*(lane>>4)+i]; B: [k][col=16n+(lane&15)]
//   D: lane holds D[row=rb+4*(lane>>4)+r][col=16n+(lane&15)]
// ---------------------------------------------------------------------------
__global__ __launch_bounds__(256, 4) void ssd_k1(
    const float* __restrict__ X, const float* __restrict__ A,
    const float* __restrict__ B, const float* __restrict__ C,
    const float* __restrict__ l2ab, const float* __restrict__ l2b,
    const float* __restrict__ ema,
    unsigned short* __restrict__ yw, unsigned short* __restrict__ hf,
    float* __restrict__ dcb, float* __restrict__ dfs)
{
    __shared__ __align__(16) short R1[CH * LDT];   // X nat -> XT
    __shared__ __align__(16) short R2[CH * LDT];   // B nat -> B'T (dte-scaled)
    __shared__ __align__(16) short R3[CH * LDT];   // C nat -> T
    __shared__ __align__(16) float red[4];

    const int tid   = threadIdx.x;
    const int blk   = blockIdx.x;          // (bb*NH + h)*32 + npair
    const int npair = blk & 31;
    const int h     = (blk >> 5) & (NH - 1);
    const int bb    = blk >> 9;

    const int lane = tid & 63;
    const int w    = tid >> 6;
    const int rb   = 16 * w;
    const int fr   = lane & 15;
    const int gq   = lane >> 4;
    const int g4   = 4 * gq;
    const int ko   = 8 * gq;
    const int rot  = (fr >> 1) & 3;

    const int sc = tid >> 4, sd0 = (tid & 15) * 4;   // stage coords (m-step +16 rows)

    float4 px[4], pb[4], pc[4];
    float  pa;

    // ---- issue loads for first chunk ----
    {
        const int gc = 2 * npair;
        const size_t bg = ((size_t)(bb * LSEQ + gc * CH) * NH + h) * DH;
        #pragma unroll
        for (int m = 0; m < 4; ++m) {
            size_t g = bg + (size_t)(sc + 16 * m) * 1024 + sd0;
            px[m] = ld4(&X[g]); pb[m] = ld4(&B[g]); pc[m] = ld4(&C[g]);
        }
        pa = A[(size_t)(bb * LSEQ + gc * CH + lane) * NH + h];
    }

    const f32x4 zf = {0.f, 0.f, 0.f, 0.f};

    #pragma unroll
    for (int it = 0; it < 2; ++it) {
        const int gc   = 2 * npair + it;
        const int gblk = ((bb * NH + h) << 6) | gc;
        const size_t bg = ((size_t)(bb * LSEQ + gc * CH) * NH + h) * DH;

        if (it) barrier_lds();   // prior iter's LDS reads complete

        // ---- stage current chunk from regs (vmcnt waits land here) ----
        float aval = pa;
        #pragma unroll
        for (int m = 0; m < 4; ++m) {
            int c = sc + 16 * m;
            *reinterpret_cast<s16x4*>(&R1[c * LDT + sd0]) = pack4(px[m].x, px[m].y, px[m].z, px[m].w);
            *reinterpret_cast<s16x4*>(&R2[c * LDT + sd0]) = pack4(pb[m].x, pb[m].y, pb[m].z, pb[m].w);
            *reinterpret_cast<s16x4*>(&R3[c * LDT + sd0]) = pack4(pc[m].x, pc[m].y, pc[m].z, pc[m].w);
        }
        // ---- issue next chunk's loads (stay in flight across raw barriers) ----
        if (it == 0) {
            const int gn = 2 * npair + 1;
            const size_t bn = ((size_t)(bb * LSEQ + gn * CH) * NH + h) * DH;
            #pragma unroll
            for (int m = 0; m < 4; ++m) {
                size_t g = bn + (size_t)(sc + 16 * m) * 1024 + sd0;
                px[m] = ld4(&X[g]); pb[m] = ld4(&B[g]); pc[m] = ld4(&C[g]);
            }
            pa = A[(size_t)(bb * LSEQ + gn * CH + lane) * NH + h];
        }
        barrier_lds();   // sync0: tiles visible

        // ---- phase 2: GX,GB per-n (transient), CB kept; ss = sum GX*GB ----
        bf16x8 aX0 = *reinterpret_cast<const bf16x8*>(&R1[(rb + fr) * LDT + 0  + ko]);
        bf16x8 aX1 = *reinterpret_cast<const bf16x8*>(&R1[(rb + fr) * LDT + 32 + ko]);
        bf16x8 aB0 = *reinterpret_cast<const bf16x8*>(&R2[(rb + fr) * LDT + 0  + ko]);
        bf16x8 aB1 = *reinterpret_cast<const bf16x8*>(&R2[(rb + fr) * LDT + 32 + ko]);
        bf16x8 aC0 = *reinterpret_cast<const bf16x8*>(&R3[(rb + fr) * LDT + 0  + ko]);
        bf16x8 aC1 = *reinterpret_cast<const bf16x8*>(&R3[(rb + fr) * LDT + 32 + ko]);
        f32x4 aCB[4];
        float ss = 0.f;
        #pragma unroll
        for (int n = 0; n < 4; ++n) {
            bf16x8 bX0 = *reinterpret_cast<const bf16x8*>(&R1[(16 * n + fr) * LDT + 0  + ko]);
            bf16x8 bX1 = *reinterpret_cast<const bf16x8*>(&R1[(16 * n + fr) * LDT + 32 + ko]);
            bf16x8 bB0 = *reinterpret_cast<const bf16x8*>(&R2[(16 * n + fr) * LDT + 0  + ko]);
            bf16x8 bB1 = *reinterpret_cast<const bf16x8*>(&R2[(16 * n + fr) * LDT + 32 + ko]);
            f32x4 gx = MFMA16(aX1, bX1, MFMA16(aX0, bX0, zf));
            f32x4 gb = MFMA16(aB1, bB1, MFMA16(aB0, bB0, zf));
            aCB[n]   = MFMA16(aC1, bB1, MFMA16(aC0, bB0, zf));
            #pragma unroll
            for (int r = 0; r < 4; ++r) ss = fmaf(gx[r], gb[r], ss);
        }
        #pragma unroll
        for (int off = 32; off > 0; off >>= 1) ss += __shfl_down(ss, off, 64);
        if (lane == 0) red[w] = ss;
        barrier_lds();   // sync1

        // ---- gate + scan, redundantly in every wave ----
        float4 rv = *reinterpret_cast<const float4*>(red);
        float surprise = (rv.x + rv.y + rv.z + rv.w) * (1.f / 4096.f);
        float l2c   = fminf(fmaxf(l2ab[h], -3.32f), -0.015f);
        float ab_   = 1.f - exp2f(l2c);
        float bt    = exp2f(fminf(fmaxf(l2b[h], -2.f), 2.f));
        float nrm   = surprise / (ema[h] + 1e-6f);
        float boost = fmaxf(tanhf(bt * nrm), 0.f);
        float alpha = fminf(fmaxf(ab_ + (1.f - ab_) * boost, 0.01f), 0.999f);
        float scale = 1.f - alpha;
        float v = aval * scale;
        #pragma unroll
        for (int off = 1; off < 64; off <<= 1) {
            float t = __shfl_up(v, off, 64);
            if (lane >= off) v += t;
        }
        float tot  = __shfl(v, 63, 64);
        float epv  = __expf(v);
        float env  = __expf(-v);
        float dtev = __expf(tot - v);
        if (w == 0) {
            dfs[(size_t)gblk * CH + lane] = epv;
            if (lane == 63) dcb[gblk] = __expf(tot);
        }

        // ---- T[i][j] -> R3 ----
        {
            float epi[4], enj[4];
            #pragma unroll
            for (int r = 0; r < 4; ++r) epi[r] = __shfl(epv, rb + g4 + r, 64);
            #pragma unroll
            for (int n = 0; n < 4; ++n) enj[n] = __shfl(env, 16 * n + fr, 64);
            #pragma unroll
            for (int n = 0; n < 4; ++n)
                #pragma unroll
                for (int r = 0; r < 4; ++r) {
                    int i = rb + g4 + r, j = 16 * n + fr;
                    float val = (j <= i) ? epi[r] * enj[n] * aCB[n][r] : 0.f;
                    R3[i * LDT + j] = f2b(val);
                }
        }

        // ---- butterfly transpose of R1,R2 (rotated c0 breaks write conflicts) ----
        s16x4 outX[4], outB[4];
        const int d0 = 4 * fr;
        #pragma unroll
        for (int m = 0; m < 4; ++m) {
            int c0 = 16 * w + 4 * ((m + rot) & 3);
            uint2 mx = *reinterpret_cast<const uint2*>(&R1[(c0 + gq) * LDT + d0]);
            uint2 mb = *reinterpret_cast<const uint2*>(&R2[(c0 + gq) * LDT + d0]);
            uint2 px_ = sx2(mx, 16), pb_ = sx2(mb, 16);
            uint2 xe = (gq & 1) ? px_ : mx, xo = (gq & 1) ? mx : px_;
            uint2 be = (gq & 1) ? pb_ : mb, bo = (gq & 1) ? mb : pb_;
            uint2 xpe = sx2(xe, 32), xpo = sx2(xo, 32);
            uint2 bpe = sx2(be, 32), bpo = sx2(bo, 32);
            uint2 xr0 = (gq & 2) ? xpe : xe, xr1 = (gq & 2) ? xpo : xo;
            uint2 xr2 = (gq & 2) ? xe : xpe, xr3 = (gq & 2) ? xo : xpo;
            uint2 br0 = (gq & 2) ? bpe : be, br1 = (gq & 2) ? bpo : bo;
            uint2 br2 = (gq & 2) ? be : bpe, br3 = (gq & 2) ? bo : bpo;
            s16x4 ox; ox.x = ext4(xr0, gq); ox.y = ext4(xr1, gq);
                      ox.z = ext4(xr2, gq); ox.w = ext4(xr3, gq);
            outX[m] = ox;
            float dt0 = __shfl(dtev, c0 + 0, 64), dt1 = __shfl(dtev, c0 + 1, 64);
            float dt2 = __shfl(dtev, c0 + 2, 64), dt3 = __shfl(dtev, c0 + 3, 64);
            s16x4 ob;
            ob.x = f2b(b2f(ext4(br0, gq)) * dt0);
            ob.y = f2b(b2f(ext4(br1, gq)) * dt1);
            ob.z = f2b(b2f(ext4(br2, gq)) * dt2);
            ob.w = f2b(b2f(ext4(br3, gq)) * dt3);
            outB[m] = ob;
        }
        barrier_lds();   // sync2: natural reads complete

        #pragma unroll
        for (int m = 0; m < 4; ++m) {
            int c0 = 16 * w + 4 * ((m + rot) & 3);
            *reinterpret_cast<s16x4*>(&R1[(d0 + gq) * LDT + c0]) = outX[m];
            *reinterpret_cast<s16x4*>(&R2[(d0 + gq) * LDT + c0]) = outB[m];
        }
        barrier_lds();   // sync3: XT, B'T, T visible

        // ---- Y_intra^T = MFMA(A=XT,B=T); h_final = MFMA(A=B'T,B=XT) ----
        f32x4 acc2[4] = {zf, zf, zf, zf};
        f32x4 acc3[4] = {zf, zf, zf, zf};
        #pragma unroll
        for (int k0 = 0; k0 < 64; k0 += 32) {
            bf16x8 aX = *reinterpret_cast<const bf16x8*>(&R1[(rb + fr) * LDT + k0 + ko]);
            bf16x8 aB = *reinterpret_cast<const bf16x8*>(&R2[(rb + fr) * LDT + k0 + ko]);
            #pragma unroll
            for (int n = 0; n < 4; ++n) {
                bf16x8 bT = *reinterpret_cast<const bf16x8*>(&R3[(16 * n + fr) * LDT + k0 + ko]);
                bf16x8 bX = *reinterpret_cast<const bf16x8*>(&R1[(16 * n + fr) * LDT + k0 + ko]);
                acc2[n] = MFMA16(aX, bT, acc2[n]);
                acc3[n] = MFMA16(aB, bX, acc3[n]);
            }
        }
        #pragma unroll
        for (int n = 0; n < 4; ++n) {
            int colI = 16 * n + fr;
            s16x4 y4 = pack4(acc2[n][0], acc2[n][1], acc2[n][2], acc2[n][3]);
            s16x4 h4 = pack4(acc3[n][0], acc3[n][1], acc3[n][2], acc3[n][3]);
            *reinterpret_cast<s16x4*>(&yw[(size_t)gblk * 4096 + colI * 64 + rb + g4]) = y4;
            *reinterpret_cast<s16x4*>(&hf[(size_t)gblk * 4096 + colI * 64 + rb + g4]) = h4;
        }
    }
}

// ---------------------------------------------------------------------------
// Kernel 2: sequential inter-chunk scan, in place on bf16 hf.
// 256 blocks x 256 threads; each thread owns 2 state elements (one uint).
// ---------------------------------------------------------------------------
__global__ __launch_bounds__(256) void ssd_k2(
    unsigned int* __restrict__ hfU, const float* __restrict__ dcb)
{
    __shared__ float sdc[NCH];
    const int tid = threadIdx.x;
    const int bh  = blockIdx.x >> 3;
    const int sub = blockIdx.x & 7;
    if (tid < NCH) sdc[tid] = dcb[bh * NCH + tid];
    __syncthreads();
    const size_t base = (size_t)bh * NCH * 2048 + sub * 256 + tid;

    float c0 = 0.f, c1 = 0.f;
    unsigned int cur[8];
    #pragma unroll
    for (int kk = 0; kk < 8; ++kk) cur[kk] = hfU[base + (size_t)kk * 2048];
    #pragma unroll
    for (int kb = 0; kb < 8; ++kb) {
        unsigned int nxt[8];
        if (kb < 7) {
            #pragma unroll
            for (int kk = 0; kk < 8; ++kk)
                nxt[kk] = hfU[base + (size_t)(8 * kb + 8 + kk) * 2048];
        }
        #pragma unroll
        for (int kk = 0; kk < 8; ++kk) {
            int k = 8 * kb + kk;
            unsigned int u = cur[kk];
            union { unsigned int q; float f; } lo, hi;
            lo.q = u << 16;
            hi.q = u & 0xffff0000u;
            unsigned int packed = (unsigned int)(unsigned short)f2b(c0)
                                | ((unsigned int)(unsigned short)f2b(c1) << 16);
            hfU[base + (size_t)k * 2048] = packed;
            float d = sdc[k];
            c0 = fmaf(d, c0, lo.f);
            c1 = fmaf(d, c1, hi.f);
        }
        if (kb < 7) {
            #pragma unroll
            for (int kk = 0; kk < 8; ++kk) cur[kk] = nxt[kk];
        }
    }
}

// ---------------------------------------------------------------------------
// Kernel 3: Y[i][p] = yw[i][p] + dfs[i] * (C @ h_inter)[i][p].
// Y_inter^T = MFMA(A=sHt (h^T[p][s], native hf layout), B=sC2 (C[i][s]))
// -> D[p][i]; float4 stores to Y (p fastest). One block per (b,h,n).
// ---------------------------------------------------------------------------
__global__ __launch_bounds__(256) void ssd_k3(
    const float* __restrict__ C, const unsigned short* __restrict__ hI,
    const unsigned short* __restrict__ yw, const float* __restrict__ dfs,
    float* __restrict__ Y)
{
    __shared__ __align__(16) short sHt[CH * LDT];
    __shared__ __align__(16) short sC2[CH * LDT];
    __shared__ float sF[CH];

    const int tid  = threadIdx.x;
    const int blk  = blockIdx.x;
    const int nidx = blk & (NCH - 1);
    const int h    = (blk >> 6) & (NH - 1);
    const int bb   = blk >> 10;
    const size_t base = ((size_t)(bb * LSEQ + nidx * CH) * NH + h) * DH;

    #pragma unroll
    for (int m = 0; m < 2; ++m) {
        int idx = tid + 256 * m;
        int row = idx >> 3, c8 = (idx & 7) * 8;
        bf16x8 v = *reinterpret_cast<const bf16x8*>(&hI[(size_t)blk * 4096 + row * 64 + c8]);
        *reinterpret_cast<bf16x8*>(&sHt[row * LDT + c8]) = v;
    }
    #pragma unroll
    for (int m = 0; m < 4; ++m) {
        int p = tid + 256 * m;
        int row = p >> 4, d0 = (p & 15) * 4;
        float4 cv = ld4(&C[base + (size_t)row * 1024 + d0]);
        *reinterpret_cast<s16x4*>(&sC2[row * LDT + d0]) = pack4(cv.x, cv.y, cv.z, cv.w);
    }
    if (tid < CH) sF[tid] = dfs[(size_t)blk * CH + tid];
    __syncthreads();

    const int lane = tid & 63;
    const int w    = tid >> 6;
    const int rb   = 16 * w;
    const int fr   = lane & 15;
    const int g4   = 4 * (lane >> 4);
    const int ko   = 8 * (lane >> 4);
    const f32x4 zf = {0.f, 0.f, 0.f, 0.f};

    f32x4 acc[4] = {zf, zf, zf, zf};
    #pragma unroll
    for (int k0 = 0; k0 < 64; k0 += 32) {
        bf16x8 a = *reinterpret_cast<const bf16x8*>(&sHt[(rb + fr) * LDT + k0 + ko]);
        #pragma unroll
        for (int n = 0; n < 4; ++n) {
            bf16x8 b = *reinterpret_cast<const bf16x8*>(&sC2[(16 * n + fr) * LDT + k0 + ko]);
            acc[n] = MFMA16(a, b, acc[n]);
        }
    }
    #pragma unroll
    for (int n = 0; n < 4; ++n) {
        int i  = 16 * n + fr;
        int p0 = rb + g4;
        float f = sF[i];
        const unsigned short* ywp = &yw[(size_t)blk * 4096 + i * 64 + p0];
        float4 o;
        o.x = fmaf(f, acc[n][0], b2f((short)ywp[0]));
        o.y = fmaf(f, acc[n][1], b2f((short)ywp[1]));
        o.z = fmaf(f, acc[n][2], b2f((short)ywp[2]));
        o.w = fmaf(f, acc[n][3], b2f((short)ywp[3]));
        *reinterpret_cast<float4*>(&Y[base + (size_t)i * 1024 + p0]) = o;
    }
}

// ---------------------------------------------------------------------------
extern "C" void kernel_launch(void* const* d_in, const int* in_sizes, int n_in,
                              void* d_out, int out_size, void* d_ws, size_t ws_size,
                              hipStream_t stream)
{
    const float* X    = (const float*)d_in[0];
    const float* A    = (const float*)d_in[1];
    const float* B    = (const float*)d_in[2];
    const float* C    = (const float*)d_in[3];
    const float* l2ab = (const float*)d_in[4];
    const float* l2b  = (const float*)d_in[5];
    const float* ema  = (const float*)d_in[6];
    float* Y = (float*)d_out;

    // ws layout: hf bf16 [8388608] | yw bf16 [8388608] | dcb f32 [2048] | dfs f32 [131072]
    unsigned short* hf = (unsigned short*)d_ws;
    unsigned short* yw = hf + (size_t)8388608;
    float* dcb = (float*)(yw + (size_t)8388608);
    float* dfs = dcb + 2048;

    ssd_k1<<<1024, 256, 0, stream>>>(X, A, B, C, l2ab, l2b, ema, yw, hf, dcb, dfs);
    ssd_k2<<<256, 256, 0, stream>>>((unsigned int*)hf, dcb);
    ssd_k3<<<2048, 256, 0, stream>>>(C, hf, yw, dfs, Y);
}

// Round 6
// 66.784 us; speedup vs baseline: 1.0100x; 1.0100x over previous
//
#include <hip/hip_runtime.h>
#include <hip/hip_bf16.h>
#include <math.h>

// Problem constants (b=2, L=4096, H=16, dh=ds=64, CHUNK=64)
#define LSEQ 4096
#define NH   16
#define DH   64
#define CH   64
#define NCH  64
#define LDT  72   // bf16 LDS row stride (144B): 16B-aligned rows

typedef __attribute__((ext_vector_type(8))) short bf16x8;
typedef __attribute__((ext_vector_type(4))) short s16x4;
typedef __attribute__((ext_vector_type(4))) float f32x4;

#define MFMA16(a, b, c) __builtin_amdgcn_mfma_f32_16x16x32_bf16((a), (b), (c), 0, 0, 0)

__device__ __forceinline__ float4 ld4(const float* p) {
    return *reinterpret_cast<const float4*>(p);
}
__device__ __forceinline__ short f2b(float x) {
    __hip_bfloat16 h = __float2bfloat16(x);
    return *reinterpret_cast<short*>(&h);
}
__device__ __forceinline__ float b2f(short s) {
    union { unsigned u; float f; } v;
    v.u = ((unsigned)(unsigned short)s) << 16;
    return v.f;
}
__device__ __forceinline__ s16x4 pack4(float a, float b, float c, float d) {
    s16x4 r; r.x = f2b(a); r.y = f2b(b); r.z = f2b(c); r.w = f2b(d); return r;
}
__device__ __forceinline__ uint2 sx2(uint2 v, int m) {
    uint2 r;
    r.x = (unsigned)__shfl_xor((int)v.x, m, 64);
    r.y = (unsigned)__shfl_xor((int)v.y, m, 64);
    return r;
}
__device__ __forceinline__ short ext4(uint2 u, int g) {
    unsigned word = (g & 2) ? u.y : u.x;
    return (short)((g & 1) ? (word >> 16) : (word & 0xffffu));
}
// Barrier that drains LDS only (NOT vmcnt) — keeps prefetch global loads in
// flight across phase edges. All 256 threads execute it unconditionally.
__device__ __forceinline__ void barrier_lds() {
    __builtin_amdgcn_sched_barrier(0);
    asm volatile("s_waitcnt lgkmcnt(0)" ::: "memory");
    __builtin_amdgcn_s_barrier();
    __builtin_amdgcn_sched_barrier(0);
}

// ---------------------------------------------------------------------------
// Kernel 1: per-chunk MFMA work, 2 chunks per block, software-pipelined.
// Grid 1024 = (b,h) x 32 chunk-pairs; 256 threads = 4 waves; ~27.7 KB LDS.
// NOTE: no min-waves clause in __launch_bounds__ — round-5's (256,4) capped
// VGPR at 128 and spilled the 48-VGPR prefetch (+19.4 MB scratch traffic,
// +27 us). Unconstrained, the prefetch lives in registers spill-free.
// Schedule per chunk: stage(from regs) [+issue next chunk's loads] -> bar ->
//   GX/GB/CB MFMA + surprise reduce -> bar -> gate+scan (all waves, shfl) +
//   T->R3 + bfly-transpose read R1,R2 -> bar -> transposed writes -> bar ->
//   Y_intra^T & h_final MFMA -> global stores.
// Fragment map (m89-verified 16x16x32 bf16):
//   A: lane = A[row=rb+(lane&15)][k=8*(lane>>4)+i]; B: [k][col=16n+(lane&15)]
//   D: lane holds D[row=rb+4*(lane>>4)+r][col=16n+(lane&15)]
// ---------------------------------------------------------------------------
__global__ __launch_bounds__(256) void ssd_k1(
    const float* __restrict__ X, const float* __restrict__ A,
    const float* __restrict__ B, const float* __restrict__ C,
    const float* __restrict__ l2ab, const float* __restrict__ l2b,
    const float* __restrict__ ema,
    unsigned short* __restrict__ yw, unsigned short* __restrict__ hf,
    float* __restrict__ dcb, float* __restrict__ dfs)
{
    __shared__ __align__(16) short R1[CH * LDT];   // X nat -> XT
    __shared__ __align__(16) short R2[CH * LDT];   // B nat -> B'T (dte-scaled)
    __shared__ __align__(16) short R3[CH * LDT];   // C nat -> T
    __shared__ __align__(16) float red[4];

    const int tid   = threadIdx.x;
    const int blk   = blockIdx.x;          // (bb*NH + h)*32 + npair
    const int npair = blk & 31;
    const int h     = (blk >> 5) & (NH - 1);
    const int bb    = blk >> 9;

    const int lane = tid & 63;
    const int w    = tid >> 6;
    const int rb   = 16 * w;
    const int fr   = lane & 15;
    const int gq   = lane >> 4;
    const int g4   = 4 * gq;
    const int ko   = 8 * gq;
    const int rot  = (fr >> 1) & 3;

    const int sc = tid >> 4, sd0 = (tid & 15) * 4;   // stage coords (m-step +16 rows)

    float4 px[4], pb[4], pc[4];
    float  pa;

    // ---- issue loads for first chunk ----
    {
        const int gc = 2 * npair;
        const size_t bg = ((size_t)(bb * LSEQ + gc * CH) * NH + h) * DH;
        #pragma unroll
        for (int m = 0; m < 4; ++m) {
            size_t g = bg + (size_t)(sc + 16 * m) * 1024 + sd0;
            px[m] = ld4(&X[g]); pb[m] = ld4(&B[g]); pc[m] = ld4(&C[g]);
        }
        pa = A[(size_t)(bb * LSEQ + gc * CH + lane) * NH + h];
    }

    const f32x4 zf = {0.f, 0.f, 0.f, 0.f};

    #pragma unroll
    for (int it = 0; it < 2; ++it) {
        const int gc   = 2 * npair + it;
        const int gblk = ((bb * NH + h) << 6) | gc;

        if (it) barrier_lds();   // prior iter's LDS reads complete

        // ---- stage current chunk from regs (vmcnt waits land here) ----
        float aval = pa;
        #pragma unroll
        for (int m = 0; m < 4; ++m) {
            int c = sc + 16 * m;
            *reinterpret_cast<s16x4*>(&R1[c * LDT + sd0]) = pack4(px[m].x, px[m].y, px[m].z, px[m].w);
            *reinterpret_cast<s16x4*>(&R2[c * LDT + sd0]) = pack4(pb[m].x, pb[m].y, pb[m].z, pb[m].w);
            *reinterpret_cast<s16x4*>(&R3[c * LDT + sd0]) = pack4(pc[m].x, pc[m].y, pc[m].z, pc[m].w);
        }
        // ---- issue next chunk's loads (stay in flight across raw barriers) ----
        if (it == 0) {
            const int gn = 2 * npair + 1;
            const size_t bn = ((size_t)(bb * LSEQ + gn * CH) * NH + h) * DH;
            #pragma unroll
            for (int m = 0; m < 4; ++m) {
                size_t g = bn + (size_t)(sc + 16 * m) * 1024 + sd0;
                px[m] = ld4(&X[g]); pb[m] = ld4(&B[g]); pc[m] = ld4(&C[g]);
            }
            pa = A[(size_t)(bb * LSEQ + gn * CH + lane) * NH + h];
        }
        barrier_lds();   // sync0: tiles visible

        // ---- phase 2: GX,GB per-n (transient), CB kept; ss = sum GX*GB ----
        bf16x8 aX0 = *reinterpret_cast<const bf16x8*>(&R1[(rb + fr) * LDT + 0  + ko]);
        bf16x8 aX1 = *reinterpret_cast<const bf16x8*>(&R1[(rb + fr) * LDT + 32 + ko]);
        bf16x8 aB0 = *reinterpret_cast<const bf16x8*>(&R2[(rb + fr) * LDT + 0  + ko]);
        bf16x8 aB1 = *reinterpret_cast<const bf16x8*>(&R2[(rb + fr) * LDT + 32 + ko]);
        bf16x8 aC0 = *reinterpret_cast<const bf16x8*>(&R3[(rb + fr) * LDT + 0  + ko]);
        bf16x8 aC1 = *reinterpret_cast<const bf16x8*>(&R3[(rb + fr) * LDT + 32 + ko]);
        f32x4 aCB[4];
        float ss = 0.f;
        #pragma unroll
        for (int n = 0; n < 4; ++n) {
            bf16x8 bX0 = *reinterpret_cast<const bf16x8*>(&R1[(16 * n + fr) * LDT + 0  + ko]);
            bf16x8 bX1 = *reinterpret_cast<const bf16x8*>(&R1[(16 * n + fr) * LDT + 32 + ko]);
            bf16x8 bB0 = *reinterpret_cast<const bf16x8*>(&R2[(16 * n + fr) * LDT + 0  + ko]);
            bf16x8 bB1 = *reinterpret_cast<const bf16x8*>(&R2[(16 * n + fr) * LDT + 32 + ko]);
            f32x4 gx = MFMA16(aX1, bX1, MFMA16(aX0, bX0, zf));
            f32x4 gb = MFMA16(aB1, bB1, MFMA16(aB0, bB0, zf));
            aCB[n]   = MFMA16(aC1, bB1, MFMA16(aC0, bB0, zf));
            #pragma unroll
            for (int r = 0; r < 4; ++r) ss = fmaf(gx[r], gb[r], ss);
        }
        #pragma unroll
        for (int off = 32; off > 0; off >>= 1) ss += __shfl_down(ss, off, 64);
        if (lane == 0) red[w] = ss;
        barrier_lds();   // sync1

        // ---- gate + scan, redundantly in every wave ----
        float4 rv = *reinterpret_cast<const float4*>(red);
        float surprise = (rv.x + rv.y + rv.z + rv.w) * (1.f / 4096.f);
        float l2c   = fminf(fmaxf(l2ab[h], -3.32f), -0.015f);
        float ab_   = 1.f - exp2f(l2c);
        float bt    = exp2f(fminf(fmaxf(l2b[h], -2.f), 2.f));
        float nrm   = surprise / (ema[h] + 1e-6f);
        float boost = fmaxf(tanhf(bt * nrm), 0.f);
        float alpha = fminf(fmaxf(ab_ + (1.f - ab_) * boost, 0.01f), 0.999f);
        float scale = 1.f - alpha;
        float v = aval * scale;
        #pragma unroll
        for (int off = 1; off < 64; off <<= 1) {
            float t = __shfl_up(v, off, 64);
            if (lane >= off) v += t;
        }
        float tot  = __shfl(v, 63, 64);
        float epv  = __expf(v);
        float env  = __expf(-v);
        float dtev = __expf(tot - v);
        if (w == 0) {
            dfs[(size_t)gblk * CH + lane] = epv;
            if (lane == 63) dcb[gblk] = __expf(tot);
        }

        // ---- T[i][j] -> R3 ----
        {
            float epi[4], enj[4];
            #pragma unroll
            for (int r = 0; r < 4; ++r) epi[r] = __shfl(epv, rb + g4 + r, 64);
            #pragma unroll
            for (int n = 0; n < 4; ++n) enj[n] = __shfl(env, 16 * n + fr, 64);
            #pragma unroll
            for (int n = 0; n < 4; ++n)
                #pragma unroll
                for (int r = 0; r < 4; ++r) {
                    int i = rb + g4 + r, j = 16 * n + fr;
                    float val = (j <= i) ? epi[r] * enj[n] * aCB[n][r] : 0.f;
                    R3[i * LDT + j] = f2b(val);
                }
        }

        // ---- butterfly transpose of R1,R2 (rotated c0 breaks write conflicts) ----
        s16x4 outX[4], outB[4];
        const int d0 = 4 * fr;
        #pragma unroll
        for (int m = 0; m < 4; ++m) {
            int c0 = 16 * w + 4 * ((m + rot) & 3);
            uint2 mx = *reinterpret_cast<const uint2*>(&R1[(c0 + gq) * LDT + d0]);
            uint2 mb = *reinterpret_cast<const uint2*>(&R2[(c0 + gq) * LDT + d0]);
            uint2 px_ = sx2(mx, 16), pb_ = sx2(mb, 16);
            uint2 xe = (gq & 1) ? px_ : mx, xo = (gq & 1) ? mx : px_;
            uint2 be = (gq & 1) ? pb_ : mb, bo = (gq & 1) ? mb : pb_;
            uint2 xpe = sx2(xe, 32), xpo = sx2(xo, 32);
            uint2 bpe = sx2(be, 32), bpo = sx2(bo, 32);
            uint2 xr0 = (gq & 2) ? xpe : xe, xr1 = (gq & 2) ? xpo : xo;
            uint2 xr2 = (gq & 2) ? xe : xpe, xr3 = (gq & 2) ? xo : xpo;
            uint2 br0 = (gq & 2) ? bpe : be, br1 = (gq & 2) ? bpo : bo;
            uint2 br2 = (gq & 2) ? be : bpe, br3 = (gq & 2) ? bo : bpo;
            s16x4 ox; ox.x = ext4(xr0, gq); ox.y = ext4(xr1, gq);
                      ox.z = ext4(xr2, gq); ox.w = ext4(xr3, gq);
            outX[m] = ox;
            float dt0 = __shfl(dtev, c0 + 0, 64), dt1 = __shfl(dtev, c0 + 1, 64);
            float dt2 = __shfl(dtev, c0 + 2, 64), dt3 = __shfl(dtev, c0 + 3, 64);
            s16x4 ob;
            ob.x = f2b(b2f(ext4(br0, gq)) * dt0);
            ob.y = f2b(b2f(ext4(br1, gq)) * dt1);
            ob.z = f2b(b2f(ext4(br2, gq)) * dt2);
            ob.w = f2b(b2f(ext4(br3, gq)) * dt3);
            outB[m] = ob;
        }
        barrier_lds();   // sync2: natural reads complete

        #pragma unroll
        for (int m = 0; m < 4; ++m) {
            int c0 = 16 * w + 4 * ((m + rot) & 3);
            *reinterpret_cast<s16x4*>(&R1[(d0 + gq) * LDT + c0]) = outX[m];
            *reinterpret_cast<s16x4*>(&R2[(d0 + gq) * LDT + c0]) = outB[m];
        }
        barrier_lds();   // sync3: XT, B'T, T visible

        // ---- Y_intra^T = MFMA(A=XT,B=T); h_final = MFMA(A=B'T,B=XT) ----
        f32x4 acc2[4] = {zf, zf, zf, zf};
        f32x4 acc3[4] = {zf, zf, zf, zf};
        #pragma unroll
        for (int k0 = 0; k0 < 64; k0 += 32) {
            bf16x8 aX = *reinterpret_cast<const bf16x8*>(&R1[(rb + fr) * LDT + k0 + ko]);
            bf16x8 aB = *reinterpret_cast<const bf16x8*>(&R2[(rb + fr) * LDT + k0 + ko]);
            #pragma unroll
            for (int n = 0; n < 4; ++n) {
                bf16x8 bT = *reinterpret_cast<const bf16x8*>(&R3[(16 * n + fr) * LDT + k0 + ko]);
                bf16x8 bX = *reinterpret_cast<const bf16x8*>(&R1[(16 * n + fr) * LDT + k0 + ko]);
                acc2[n] = MFMA16(aX, bT, acc2[n]);
                acc3[n] = MFMA16(aB, bX, acc3[n]);
            }
        }
        #pragma unroll
        for (int n = 0; n < 4; ++n) {
            int colI = 16 * n + fr;
            s16x4 y4 = pack4(acc2[n][0], acc2[n][1], acc2[n][2], acc2[n][3]);
            s16x4 h4 = pack4(acc3[n][0], acc3[n][1], acc3[n][2], acc3[n][3]);
            *reinterpret_cast<s16x4*>(&yw[(size_t)gblk * 4096 + colI * 64 + rb + g4]) = y4;
            *reinterpret_cast<s16x4*>(&hf[(size_t)gblk * 4096 + colI * 64 + rb + g4]) = h4;
        }
    }
}

// ---------------------------------------------------------------------------
// Kernel 2: sequential inter-chunk scan, in place on bf16 hf.
// 256 blocks x 256 threads; each thread owns 2 state elements (one uint).
// ---------------------------------------------------------------------------
__global__ __launch_bounds__(256) void ssd_k2(
    unsigned int* __restrict__ hfU, const float* __restrict__ dcb)
{
    __shared__ float sdc[NCH];
    const int tid = threadIdx.x;
    const int bh  = blockIdx.x >> 3;
    const int sub = blockIdx.x & 7;
    if (tid < NCH) sdc[tid] = dcb[bh * NCH + tid];
    __syncthreads();
    const size_t base = (size_t)bh * NCH * 2048 + sub * 256 + tid;

    float c0 = 0.f, c1 = 0.f;
    unsigned int cur[8];
    #pragma unroll
    for (int kk = 0; kk < 8; ++kk) cur[kk] = hfU[base + (size_t)kk * 2048];
    #pragma unroll
    for (int kb = 0; kb < 8; ++kb) {
        unsigned int nxt[8];
        if (kb < 7) {
            #pragma unroll
            for (int kk = 0; kk < 8; ++kk)
                nxt[kk] = hfU[base + (size_t)(8 * kb + 8 + kk) * 2048];
        }
        #pragma unroll
        for (int kk = 0; kk < 8; ++kk) {
            int k = 8 * kb + kk;
            unsigned int u = cur[kk];
            union { unsigned int q; float f; } lo, hi;
            lo.q = u << 16;
            hi.q = u & 0xffff0000u;
            unsigned int packed = (unsigned int)(unsigned short)f2b(c0)
                                | ((unsigned int)(unsigned short)f2b(c1) << 16);
            hfU[base + (size_t)k * 2048] = packed;
            float d = sdc[k];
            c0 = fmaf(d, c0, lo.f);
            c1 = fmaf(d, c1, hi.f);
        }
        if (kb < 7) {
            #pragma unroll
            for (int kk = 0; kk < 8; ++kk) cur[kk] = nxt[kk];
        }
    }
}

// ---------------------------------------------------------------------------
// Kernel 3: Y[i][p] = yw[i][p] + dfs[i] * (C @ h_inter)[i][p].
// Y_inter^T = MFMA(A=sHt (h^T[p][s], native hf layout), B=sC2 (C[i][s]))
// -> D[p][i]; float4 stores to Y (p fastest). One block per (b,h,n).
// ---------------------------------------------------------------------------
__global__ __launch_bounds__(256) void ssd_k3(
    const float* __restrict__ C, const unsigned short* __restrict__ hI,
    const unsigned short* __restrict__ yw, const float* __restrict__ dfs,
    float* __restrict__ Y)
{
    __shared__ __align__(16) short sHt[CH * LDT];
    __shared__ __align__(16) short sC2[CH * LDT];
    __shared__ float sF[CH];

    const int tid  = threadIdx.x;
    const int blk  = blockIdx.x;
    const int nidx = blk & (NCH - 1);
    const int h    = (blk >> 6) & (NH - 1);
    const int bb   = blk >> 10;
    const size_t base = ((size_t)(bb * LSEQ + nidx * CH) * NH + h) * DH;

    #pragma unroll
    for (int m = 0; m < 2; ++m) {
        int idx = tid + 256 * m;
        int row = idx >> 3, c8 = (idx & 7) * 8;
        bf16x8 v = *reinterpret_cast<const bf16x8*>(&hI[(size_t)blk * 4096 + row * 64 + c8]);
        *reinterpret_cast<bf16x8*>(&sHt[row * LDT + c8]) = v;
    }
    #pragma unroll
    for (int m = 0; m < 4; ++m) {
        int p = tid + 256 * m;
        int row = p >> 4, d0 = (p & 15) * 4;
        float4 cv = ld4(&C[base + (size_t)row * 1024 + d0]);
        *reinterpret_cast<s16x4*>(&sC2[row * LDT + d0]) = pack4(cv.x, cv.y, cv.z, cv.w);
    }
    if (tid < CH) sF[tid] = dfs[(size_t)blk * CH + tid];
    __syncthreads();

    const int lane = tid & 63;
    const int w    = tid >> 6;
    const int rb   = 16 * w;
    const int fr   = lane & 15;
    const int g4   = 4 * (lane >> 4);
    const int ko   = 8 * (lane >> 4);
    const f32x4 zf = {0.f, 0.f, 0.f, 0.f};

    f32x4 acc[4] = {zf, zf, zf, zf};
    #pragma unroll
    for (int k0 = 0; k0 < 64; k0 += 32) {
        bf16x8 a = *reinterpret_cast<const bf16x8*>(&sHt[(rb + fr) * LDT + k0 + ko]);
        #pragma unroll
        for (int n = 0; n < 4; ++n) {
            bf16x8 b = *reinterpret_cast<const bf16x8*>(&sC2[(16 * n + fr) * LDT + k0 + ko]);
            acc[n] = MFMA16(a, b, acc[n]);
        }
    }
    #pragma unroll
    for (int n = 0; n < 4; ++n) {
        int i  = 16 * n + fr;
        int p0 = rb + g4;
        float f = sF[i];
        const unsigned short* ywp = &yw[(size_t)blk * 4096 + i * 64 + p0];
        float4 o;
        o.x = fmaf(f, acc[n][0], b2f((short)ywp[0]));
        o.y = fmaf(f, acc[n][1], b2f((short)ywp[1]));
        o.z = fmaf(f, acc[n][2], b2f((short)ywp[2]));
        o.w = fmaf(f, acc[n][3], b2f((short)ywp[3]));
        *reinterpret_cast<float4*>(&Y[base + (size_t)i * 1024 + p0]) = o;
    }
}

// ---------------------------------------------------------------------------
extern "C" void kernel_launch(void* const* d_in, const int* in_sizes, int n_in,
                              void* d_out, int out_size, void* d_ws, size_t ws_size,
                              hipStream_t stream)
{
    const float* X    = (const float*)d_in[0];
    const float* A    = (const float*)d_in[1];
    const float* B    = (const float*)d_in[2];
    const float* C    = (const float*)d_in[3];
    const float* l2ab = (const float*)d_in[4];
    const float* l2b  = (const float*)d_in[5];
    const float* ema  = (const float*)d_in[6];
    float* Y = (float*)d_out;

    // ws layout: hf bf16 [8388608] | yw bf16 [8388608] | dcb f32 [2048] | dfs f32 [131072]
    unsigned short* hf = (unsigned short*)d_ws;
    unsigned short* yw = hf + (size_t)8388608;
    float* dcb = (float*)(yw + (size_t)8388608);
    float* dfs = dcb + 2048;

    ssd_k1<<<1024, 256, 0, stream>>>(X, A, B, C, l2ab, l2b, ema, yw, hf, dcb, dfs);
    ssd_k2<<<256, 256, 0, stream>>>((unsigned int*)hf, dcb);
    ssd_k3<<<2048, 256, 0, stream>>>(C, hf, yw, dfs, Y);
}

// Round 7
// 57.297 us; speedup vs baseline: 1.1773x; 1.1656x over previous
//
#include <hip/hip_runtime.h>
#include <hip/hip_bf16.h>
#include <math.h>

// Problem constants (b=2, L=4096, H=16, dh=ds=64, CHUNK=64)
#define LSEQ 4096
#define NH   16
#define DH   64
#define CH   64
#define NCH  64

typedef __attribute__((ext_vector_type(8))) short bf16x8;
typedef __attribute__((ext_vector_type(4))) short s16x4;
typedef __attribute__((ext_vector_type(4))) float f32x4;

#define MFMA16(a, b, c) __builtin_amdgcn_mfma_f32_16x16x32_bf16((a), (b), (c), 0, 0, 0)

// XOR-swizzled LDS index (shorts): tile is [64][64] shorts (128B rows).
// byte ^= ((row&7)<<4)  <=>  short-col ^= ((row&7)<<3). Keeps 16B/8B/2B ops
// aligned+bijective; makes row-strided frag reads 2-way (free) at stride 64.
__device__ __forceinline__ int swz(int row, int col) {
    return (row << 6) + (col ^ ((row & 7) << 3));
}

__device__ __forceinline__ float4 ld4(const float* p) {
    return *reinterpret_cast<const float4*>(p);
}
__device__ __forceinline__ short f2b(float x) {
    __hip_bfloat16 h = __float2bfloat16(x);
    return *reinterpret_cast<short*>(&h);
}
__device__ __forceinline__ float b2f(short s) {
    union { unsigned u; float f; } v;
    v.u = ((unsigned)(unsigned short)s) << 16;
    return v.f;
}
__device__ __forceinline__ s16x4 pack4(float a, float b, float c, float d) {
    s16x4 r; r.x = f2b(a); r.y = f2b(b); r.z = f2b(c); r.w = f2b(d); return r;
}
__device__ __forceinline__ uint2 sx2(uint2 v, int m) {
    uint2 r;
    r.x = (unsigned)__shfl_xor((int)v.x, m, 64);
    r.y = (unsigned)__shfl_xor((int)v.y, m, 64);
    return r;
}
__device__ __forceinline__ short ext4(uint2 u, int g) {
    unsigned word = (g & 2) ? u.y : u.x;
    return (short)((g & 1) ? (word >> 16) : (word & 0xffffu));
}

// ---------------------------------------------------------------------------
// Kernel 1: per-chunk MFMA work. One block per (b,h,n) — round-4 structure
// (2048 blocks, plain __syncthreads; the 2-chunk pipeline of r5/r6 regressed).
// Gram-trick schedule, 4 barriers, 3 swizzled 8KB tiles = 24.6KB -> 6 blk/CU.
//   stage naturals X->R1, B->R2, C->R3 (vectorized, conflict-free)
//   sync0; GX=X.X^T, GB=B.B^T, CB=C.B^T (natural); ss=sum GX*GB -> red
//   sync1; gate+scan redundantly per wave (shfl); T->R3 (C dead);
//          bfly-transpose read R1,R2 in regs
//   sync2; write XT->R1, dte-scaled B'^T->R2 (in place)
//   sync3; Y_intra^T = MFMA(A=XT,B=T) -> yw ; h_final = MFMA(A=B'T,B=XT) -> hf
// Fragment map (m89-verified 16x16x32 bf16):
//   A: lane = A[row=rb+(lane&15)][k=8*(lane>>4)+i]; B: [k][col=16n+(lane&15)]
//   D: lane holds D[row=rb+4*(lane>>4)+r][col=16n+(lane&15)]
// ---------------------------------------------------------------------------
__global__ __launch_bounds__(256) void ssd_k1(
    const float* __restrict__ X, const float* __restrict__ A,
    const float* __restrict__ B, const float* __restrict__ C,
    const float* __restrict__ l2ab, const float* __restrict__ l2b,
    const float* __restrict__ ema,
    unsigned short* __restrict__ yw, unsigned short* __restrict__ hf,
    float* __restrict__ dcb, float* __restrict__ dfs)
{
    __shared__ __align__(16) short R1[CH * 64];   // X nat -> XT
    __shared__ __align__(16) short R2[CH * 64];   // B nat -> B'T (dte-scaled)
    __shared__ __align__(16) short R3[CH * 64];   // C nat -> T
    __shared__ __align__(16) float red[4];

    const int tid  = threadIdx.x;
    const int blk  = blockIdx.x;
    const int nidx = blk & (NCH - 1);
    const int h    = (blk >> 6) & (NH - 1);
    const int bb   = blk >> 10;
    const size_t base = ((size_t)(bb * LSEQ + nidx * CH) * NH + h) * DH;

    const int lane = tid & 63;
    const int w    = tid >> 6;
    const int rb   = 16 * w;
    const int fr   = lane & 15;
    const int gq   = lane >> 4;
    const int g4   = 4 * gq;
    const int ko   = 8 * gq;
    const int rot  = (fr >> 1) & 3;

    const int sc = tid >> 4, sd0 = (tid & 15) * 4;

    // ---- stage naturals (vectorized 8B LDS writes, conflict-free) ----
    #pragma unroll
    for (int m = 0; m < 4; ++m) {
        int c = sc + 16 * m;
        size_t g = base + (size_t)c * 1024 + sd0;
        float4 xv = ld4(&X[g]);
        float4 bv = ld4(&B[g]);
        float4 cv = ld4(&C[g]);
        *reinterpret_cast<s16x4*>(&R1[swz(c, sd0)]) = pack4(xv.x, xv.y, xv.z, xv.w);
        *reinterpret_cast<s16x4*>(&R2[swz(c, sd0)]) = pack4(bv.x, bv.y, bv.z, bv.w);
        *reinterpret_cast<s16x4*>(&R3[swz(c, sd0)]) = pack4(cv.x, cv.y, cv.z, cv.w);
    }
    float aval = A[(size_t)(bb * LSEQ + nidx * CH + lane) * NH + h];
    __syncthreads();   // sync0

    const f32x4 zf = {0.f, 0.f, 0.f, 0.f};

    // ---- phase 2: GX, GB (transient), CB kept; ss = sum GX*GB ----
    bf16x8 aX0 = *reinterpret_cast<const bf16x8*>(&R1[swz(rb + fr, 0  + ko)]);
    bf16x8 aX1 = *reinterpret_cast<const bf16x8*>(&R1[swz(rb + fr, 32 + ko)]);
    bf16x8 aB0 = *reinterpret_cast<const bf16x8*>(&R2[swz(rb + fr, 0  + ko)]);
    bf16x8 aB1 = *reinterpret_cast<const bf16x8*>(&R2[swz(rb + fr, 32 + ko)]);
    bf16x8 aC0 = *reinterpret_cast<const bf16x8*>(&R3[swz(rb + fr, 0  + ko)]);
    bf16x8 aC1 = *reinterpret_cast<const bf16x8*>(&R3[swz(rb + fr, 32 + ko)]);
    f32x4 aCB[4];
    float ss = 0.f;
    #pragma unroll
    for (int n = 0; n < 4; ++n) {
        bf16x8 bX0 = *reinterpret_cast<const bf16x8*>(&R1[swz(16 * n + fr, 0  + ko)]);
        bf16x8 bX1 = *reinterpret_cast<const bf16x8*>(&R1[swz(16 * n + fr, 32 + ko)]);
        bf16x8 bB0 = *reinterpret_cast<const bf16x8*>(&R2[swz(16 * n + fr, 0  + ko)]);
        bf16x8 bB1 = *reinterpret_cast<const bf16x8*>(&R2[swz(16 * n + fr, 32 + ko)]);
        f32x4 gx = MFMA16(aX1, bX1, MFMA16(aX0, bX0, zf));
        f32x4 gb = MFMA16(aB1, bB1, MFMA16(aB0, bB0, zf));
        aCB[n]   = MFMA16(aC1, bB1, MFMA16(aC0, bB0, zf));
        #pragma unroll
        for (int r = 0; r < 4; ++r) ss = fmaf(gx[r], gb[r], ss);
    }
    #pragma unroll
    for (int off = 32; off > 0; off >>= 1) ss += __shfl_down(ss, off, 64);
    if (lane == 0) red[w] = ss;
    __syncthreads();   // sync1

    // ---- gate + scan, redundantly in every wave (shfl, no LDS tables) ----
    float4 rv = *reinterpret_cast<const float4*>(red);
    float surprise = (rv.x + rv.y + rv.z + rv.w) * (1.f / 4096.f);
    float l2c   = fminf(fmaxf(l2ab[h], -3.32f), -0.015f);
    float ab_   = 1.f - exp2f(l2c);
    float bt    = exp2f(fminf(fmaxf(l2b[h], -2.f), 2.f));
    float nrm   = surprise / (ema[h] + 1e-6f);
    float boost = fmaxf(tanhf(bt * nrm), 0.f);
    float alpha = fminf(fmaxf(ab_ + (1.f - ab_) * boost, 0.01f), 0.999f);
    float scale = 1.f - alpha;
    float v = aval * scale;
    #pragma unroll
    for (int off = 1; off < 64; off <<= 1) {
        float t = __shfl_up(v, off, 64);
        if (lane >= off) v += t;
    }
    float tot  = __shfl(v, 63, 64);
    float epv  = __expf(v);
    float env  = __expf(-v);
    float dtev = __expf(tot - v);
    if (w == 0) {
        dfs[(size_t)blk * CH + lane] = epv;
        if (lane == 63) dcb[blk] = __expf(tot);
    }

    // ---- T[i][j] = (j<=i) ? exp(Acs_i - Acs_j)*CB[i][j] : 0  -> R3 ----
    {
        float epi[4], enj[4];
        #pragma unroll
        for (int r = 0; r < 4; ++r) epi[r] = __shfl(epv, rb + g4 + r, 64);
        #pragma unroll
        for (int n = 0; n < 4; ++n) enj[n] = __shfl(env, 16 * n + fr, 64);
        #pragma unroll
        for (int n = 0; n < 4; ++n)
            #pragma unroll
            for (int r = 0; r < 4; ++r) {
                int i = rb + g4 + r, j = 16 * n + fr;
                float val = (j <= i) ? epi[r] * enj[n] * aCB[n][r] : 0.f;
                R3[swz(i, j)] = f2b(val);
            }
    }

    // ---- butterfly transpose of R1,R2 (rot breaks write-bank aliasing) ----
    s16x4 outX[4], outB[4];
    const int d0 = 4 * fr;
    #pragma unroll
    for (int m = 0; m < 4; ++m) {
        int c0 = 16 * w + 4 * ((m + rot) & 3);
        uint2 mx = *reinterpret_cast<const uint2*>(&R1[swz(c0 + gq, d0)]);
        uint2 mb = *reinterpret_cast<const uint2*>(&R2[swz(c0 + gq, d0)]);
        uint2 px_ = sx2(mx, 16), pb_ = sx2(mb, 16);
        uint2 xe = (gq & 1) ? px_ : mx, xo = (gq & 1) ? mx : px_;
        uint2 be = (gq & 1) ? pb_ : mb, bo = (gq & 1) ? mb : pb_;
        uint2 xpe = sx2(xe, 32), xpo = sx2(xo, 32);
        uint2 bpe = sx2(be, 32), bpo = sx2(bo, 32);
        uint2 xr0 = (gq & 2) ? xpe : xe, xr1 = (gq & 2) ? xpo : xo;
        uint2 xr2 = (gq & 2) ? xe : xpe, xr3 = (gq & 2) ? xo : xpo;
        uint2 br0 = (gq & 2) ? bpe : be, br1 = (gq & 2) ? bpo : bo;
        uint2 br2 = (gq & 2) ? be : bpe, br3 = (gq & 2) ? bo : bpo;
        s16x4 ox; ox.x = ext4(xr0, gq); ox.y = ext4(xr1, gq);
                  ox.z = ext4(xr2, gq); ox.w = ext4(xr3, gq);
        outX[m] = ox;
        float dt0 = __shfl(dtev, c0 + 0, 64), dt1 = __shfl(dtev, c0 + 1, 64);
        float dt2 = __shfl(dtev, c0 + 2, 64), dt3 = __shfl(dtev, c0 + 3, 64);
        s16x4 ob;
        ob.x = f2b(b2f(ext4(br0, gq)) * dt0);
        ob.y = f2b(b2f(ext4(br1, gq)) * dt1);
        ob.z = f2b(b2f(ext4(br2, gq)) * dt2);
        ob.w = f2b(b2f(ext4(br3, gq)) * dt3);
        outB[m] = ob;
    }
    __syncthreads();   // sync2: all natural reads complete

    #pragma unroll
    for (int m = 0; m < 4; ++m) {
        int c0 = 16 * w + 4 * ((m + rot) & 3);
        *reinterpret_cast<s16x4*>(&R1[swz(d0 + gq, c0)]) = outX[m];
        *reinterpret_cast<s16x4*>(&R2[swz(d0 + gq, c0)]) = outB[m];
    }
    __syncthreads();   // sync3: XT, B'T, T visible

    // ---- Y_intra^T = MFMA(A=XT,B=T); h_final = MFMA(A=B'T,B=XT) ----
    f32x4 acc2[4] = {zf, zf, zf, zf};
    f32x4 acc3[4] = {zf, zf, zf, zf};
    #pragma unroll
    for (int k0 = 0; k0 < 64; k0 += 32) {
        bf16x8 aX = *reinterpret_cast<const bf16x8*>(&R1[swz(rb + fr, k0 + ko)]);
        bf16x8 aB = *reinterpret_cast<const bf16x8*>(&R2[swz(rb + fr, k0 + ko)]);
        #pragma unroll
        for (int n = 0; n < 4; ++n) {
            bf16x8 bT = *reinterpret_cast<const bf16x8*>(&R3[swz(16 * n + fr, k0 + ko)]);
            bf16x8 bX = *reinterpret_cast<const bf16x8*>(&R1[swz(16 * n + fr, k0 + ko)]);
            acc2[n] = MFMA16(aX, bT, acc2[n]);
            acc3[n] = MFMA16(aB, bX, acc3[n]);
        }
    }
    #pragma unroll
    for (int n = 0; n < 4; ++n) {
        int colI = 16 * n + fr;
        s16x4 y4 = pack4(acc2[n][0], acc2[n][1], acc2[n][2], acc2[n][3]);
        s16x4 h4 = pack4(acc3[n][0], acc3[n][1], acc3[n][2], acc3[n][3]);
        *reinterpret_cast<s16x4*>(&yw[(size_t)blk * 4096 + colI * 64 + rb + g4]) = y4;
        *reinterpret_cast<s16x4*>(&hf[(size_t)blk * 4096 + colI * 64 + rb + g4]) = h4;
    }
}

// ---------------------------------------------------------------------------
// Kernel 2: sequential inter-chunk scan, in place on bf16 hf.
// 256 blocks x 256 threads; each thread owns 2 state elements (one uint).
// ---------------------------------------------------------------------------
__global__ __launch_bounds__(256) void ssd_k2(
    unsigned int* __restrict__ hfU, const float* __restrict__ dcb)
{
    __shared__ float sdc[NCH];
    const int tid = threadIdx.x;
    const int bh  = blockIdx.x >> 3;
    const int sub = blockIdx.x & 7;
    if (tid < NCH) sdc[tid] = dcb[bh * NCH + tid];
    __syncthreads();
    const size_t base = (size_t)bh * NCH * 2048 + sub * 256 + tid;

    float c0 = 0.f, c1 = 0.f;
    unsigned int cur[8];
    #pragma unroll
    for (int kk = 0; kk < 8; ++kk) cur[kk] = hfU[base + (size_t)kk * 2048];
    #pragma unroll
    for (int kb = 0; kb < 8; ++kb) {
        unsigned int nxt[8];
        if (kb < 7) {
            #pragma unroll
            for (int kk = 0; kk < 8; ++kk)
                nxt[kk] = hfU[base + (size_t)(8 * kb + 8 + kk) * 2048];
        }
        #pragma unroll
        for (int kk = 0; kk < 8; ++kk) {
            int k = 8 * kb + kk;
            unsigned int u = cur[kk];
            union { unsigned int q; float f; } lo, hi;
            lo.q = u << 16;
            hi.q = u & 0xffff0000u;
            unsigned int packed = (unsigned int)(unsigned short)f2b(c0)
                                | ((unsigned int)(unsigned short)f2b(c1) << 16);
            hfU[base + (size_t)k * 2048] = packed;
            float d = sdc[k];
            c0 = fmaf(d, c0, lo.f);
            c1 = fmaf(d, c1, hi.f);
        }
        if (kb < 7) {
            #pragma unroll
            for (int kk = 0; kk < 8; ++kk) cur[kk] = nxt[kk];
        }
    }
}

// ---------------------------------------------------------------------------
// Kernel 3: Y[i][p] = yw[i][p] + dfs[i] * (C @ h_inter)[i][p].
// Y_inter^T = MFMA(A=sHt (h^T[p][s], native hf layout), B=sC2 (C[i][s]))
// -> D[p][i]; float4 stores to Y (p fastest). One block per (b,h,n).
// Swizzled 8KB tiles -> 16.6KB LDS -> 9 blocks/CU.
// ---------------------------------------------------------------------------
__global__ __launch_bounds__(256) void ssd_k3(
    const float* __restrict__ C, const unsigned short* __restrict__ hI,
    const unsigned short* __restrict__ yw, const float* __restrict__ dfs,
    float* __restrict__ Y)
{
    __shared__ __align__(16) short sHt[CH * 64];
    __shared__ __align__(16) short sC2[CH * 64];
    __shared__ float sF[CH];

    const int tid  = threadIdx.x;
    const int blk  = blockIdx.x;
    const int nidx = blk & (NCH - 1);
    const int h    = (blk >> 6) & (NH - 1);
    const int bb   = blk >> 10;
    const size_t base = ((size_t)(bb * LSEQ + nidx * CH) * NH + h) * DH;

    #pragma unroll
    for (int m = 0; m < 2; ++m) {
        int idx = tid + 256 * m;
        int row = idx >> 3, c8 = (idx & 7) * 8;
        bf16x8 v = *reinterpret_cast<const bf16x8*>(&hI[(size_t)blk * 4096 + row * 64 + c8]);
        *reinterpret_cast<bf16x8*>(&sHt[swz(row, c8)]) = v;
    }
    #pragma unroll
    for (int m = 0; m < 4; ++m) {
        int p = tid + 256 * m;
        int row = p >> 4, d0 = (p & 15) * 4;
        float4 cv = ld4(&C[base + (size_t)row * 1024 + d0]);
        *reinterpret_cast<s16x4*>(&sC2[swz(row, d0)]) = pack4(cv.x, cv.y, cv.z, cv.w);
    }
    if (tid < CH) sF[tid] = dfs[(size_t)blk * CH + tid];
    __syncthreads();

    const int lane = tid & 63;
    const int w    = tid >> 6;
    const int rb   = 16 * w;
    const int fr   = lane & 15;
    const int g4   = 4 * (lane >> 4);
    const int ko   = 8 * (lane >> 4);
    const f32x4 zf = {0.f, 0.f, 0.f, 0.f};

    f32x4 acc[4] = {zf, zf, zf, zf};
    #pragma unroll
    for (int k0 = 0; k0 < 64; k0 += 32) {
        bf16x8 a = *reinterpret_cast<const bf16x8*>(&sHt[swz(rb + fr, k0 + ko)]);
        #pragma unroll
        for (int n = 0; n < 4; ++n) {
            bf16x8 b = *reinterpret_cast<const bf16x8*>(&sC2[swz(16 * n + fr, k0 + ko)]);
            acc[n] = MFMA16(a, b, acc[n]);
        }
    }
    #pragma unroll
    for (int n = 0; n < 4; ++n) {
        int i  = 16 * n + fr;
        int p0 = rb + g4;
        float f = sF[i];
        s16x4 y4 = *reinterpret_cast<const s16x4*>(&yw[(size_t)blk * 4096 + i * 64 + p0]);
        float4 o;
        o.x = fmaf(f, acc[n][0], b2f(y4.x));
        o.y = fmaf(f, acc[n][1], b2f(y4.y));
        o.z = fmaf(f, acc[n][2], b2f(y4.z));
        o.w = fmaf(f, acc[n][3], b2f(y4.w));
        *reinterpret_cast<float4*>(&Y[base + (size_t)i * 1024 + p0]) = o;
    }
}

// ---------------------------------------------------------------------------
extern "C" void kernel_launch(void* const* d_in, const int* in_sizes, int n_in,
                              void* d_out, int out_size, void* d_ws, size_t ws_size,
                              hipStream_t stream)
{
    const float* X    = (const float*)d_in[0];
    const float* A    = (const float*)d_in[1];
    const float* B    = (const float*)d_in[2];
    const float* C    = (const float*)d_in[3];
    const float* l2ab = (const float*)d_in[4];
    const float* l2b  = (const float*)d_in[5];
    const float* ema  = (const float*)d_in[6];
    float* Y = (float*)d_out;

    // ws layout: hf bf16 [8388608] | yw bf16 [8388608] | dcb f32 [2048] | dfs f32 [131072]
    unsigned short* hf = (unsigned short*)d_ws;
    unsigned short* yw = hf + (size_t)8388608;
    float* dcb = (float*)(yw + (size_t)8388608);
    float* dfs = dcb + 2048;

    const int nblk = 2 * NH * NCH;   // 2048
    ssd_k1<<<nblk, 256, 0, stream>>>(X, A, B, C, l2ab, l2b, ema, yw, hf, dcb, dfs);
    ssd_k2<<<256, 256, 0, stream>>>((unsigned int*)hf, dcb);
    ssd_k3<<<nblk, 256, 0, stream>>>(C, hf, yw, dfs, Y);
}